// Round 11
// baseline (5354.652 us; speedup 1.0000x reference)
//
#include <hip/hip_runtime.h>
#include <hip/hip_bf16.h>

// TensorizedRNN: m1/m2 = einsum('bj,bk,ljk->bl', h, x, W{1,2}) as bf16-MFMA GEMM
// with virtual A = h (outer) x, K = 1024*256 = 262144.
// B=1024, I2=256, H=512, N=1024 (W1||W2), J=1024.
//
// R11 = R10 structure with register-fit restored (R10 post-mortem: dropping
// amdgpu_waves_per_eu(4,4) reverted the allocator to ~64 unified regs while
// demand was ~136 -> 13 GB spill, 3.7 ms).
//  - amdgpu_waves_per_eu(4,4): 128-unified budget (proven R4/R6/R9).
//  - acc[4][4] = 64 AGPR; arch demand trimmed to ~56:
//      x PACKED (uint4 xc[4] = 16 regs; unpack on the fly, +2 VALU/word --
//      ~2k cyc/SIMD/stage, still << the 9930-cyc MFMA pipe at N=64),
//      h loaded per-half-stage (uint2 hc2[4] = 8 regs).
//  - N=64 cols/block, grid (16,16)=256 blocks = 1/CU; W read exactly once.
//  - W staged via global_load_lds (zero staging regs) -> convert phase ->
//    swizzled bf16 tile; gll(t+2) issued after convert barrier.
// Spill detector: WRITE_SIZE must be ~70-90 MB (GB-scale => revert to R9).

typedef __attribute__((ext_vector_type(8))) short short8;
typedef __attribute__((ext_vector_type(4))) float f32x4;
typedef __attribute__((ext_vector_type(2))) float f32x2;
typedef unsigned short ushort_t;

#define GLL16(gp, lp)                                                          \
  __builtin_amdgcn_global_load_lds(                                            \
      (const __attribute__((address_space(1))) void*)(gp),                     \
      (__attribute__((address_space(3))) void*)(lp), 16, 0, 0)

// f32 pair -> packed bf16 (low16 = a, high16 = b), single HW instr
__device__ __forceinline__ unsigned cvtpk(float a, float b) {
  unsigned r;
  asm("v_cvt_pk_bf16_f32 %0, %1, %2" : "=v"(r) : "v"(a), "v"(b));
  return r;
}

// packed f32 multiply, single HW instr
__device__ __forceinline__ f32x2 pkmul(f32x2 a, f32x2 b) {
  f32x2 r;
  asm("v_pk_mul_f32 %0, %1, %2" : "=v"(r) : "v"(a), "v"(b));
  return r;
}

__device__ __forceinline__ ushort_t f2bu(float f) {
  __hip_bfloat16 b = __float2bfloat16(f);
  union { __hip_bfloat16 b; ushort_t u; } cv;
  cv.b = b;
  return cv.u;
}

// ---------------- prep: hb16[b][j], xb16[b][kx], WmergeT[l][j] (all bf16) ---
__global__ void prep_k(const float* __restrict__ in0, const float* __restrict__ in1,
                       const float* __restrict__ s0, const float* __restrict__ s1,
                       const float* __restrict__ Wm,
                       ushort_t* __restrict__ hb, ushort_t* __restrict__ xb,
                       ushort_t* __restrict__ WmT) {
  __shared__ float tl[64][65];
  const int bid = blockIdx.x, t = threadIdx.x;
  if (bid < 256) {  // hb16: 1M elems, 4096/block
#pragma unroll
    for (int i = 0; i < 4; ++i) {
      int e = bid * 4096 + i * 1024 + t * 4;
      int b = e >> 10, j = e & 1023;
      const float* src = (j < 512) ? (s0 + (size_t)b * 512 + j)
                                   : (s1 + (size_t)b * 512 + j - 512);
      float4 v = *(const float4*)src;
      ushort4 o;
      o.x = f2bu(v.x); o.y = f2bu(v.y); o.z = f2bu(v.z); o.w = f2bu(v.w);
      *(ushort4*)(hb + e) = o;
    }
  } else if (bid < 272) {  // xb16: 256K elems, 16384/block
#pragma unroll
    for (int i = 0; i < 16; ++i) {
      int e = (bid - 256) * 16384 + i * 1024 + t * 4;
      int b = e >> 8, kx = e & 255;
      const float* src = (kx < 128) ? (in0 + (size_t)b * 128 + kx)
                                    : (in1 + (size_t)b * 128 + kx - 128);
      float4 v = *(const float4*)src;
      ushort4 o;
      o.x = f2bu(v.x); o.y = f2bu(v.y); o.z = f2bu(v.z); o.w = f2bu(v.w);
      *(ushort4*)(xb + e) = o;
    }
  } else {  // Wmerge [1024][512] -> WmT [512][1024], 64x64 tiles
    int q = bid - 272;           // 0..127
    int j0 = (q >> 3) * 64;
    int l0 = (q & 7) * 64;
#pragma unroll
    for (int i = 0; i < 16; ++i) {
      int idx = i * 256 + t; int r = idx >> 6, c = idx & 63;
      tl[r][c] = Wm[(size_t)(j0 + r) * 512 + l0 + c];
    }
    __syncthreads();
#pragma unroll
    for (int i = 0; i < 16; ++i) {
      int idx = i * 256 + t; int r = idx >> 6, c = idx & 63;
      WmT[(size_t)(l0 + r) * 1024 + j0 + c] = f2bu(tl[c][r]);
    }
  }
}

// ---------------- main bilinear GEMM --------------------------------------
// grid (16 ntiles, 16 kchunks) = 256 blocks, 1024 threads (16 waves), 1/CU.
// Block: all 1024 batch rows x 64 n-cols; K-chunk = 512 j's x 32 kx's,
// consumed in 64 stages of 8 j (256 K-elems per stage).
// Stage t: [B16[t&1] ready, gll(t+1) in flight]
//   compute(t): per js: 4x ds_read_b128 bfr + A-gen + 16 MFMA
//   barrier (drains gll(t+1)) -> convert -> barrier -> issue gll(t+2).
__global__ __launch_bounds__(1024)
__attribute__((amdgpu_waves_per_eu(4, 4))) void bilin_k(
    const float* __restrict__ W1, const float* __restrict__ W2,
    const ushort_t* __restrict__ hb, const ushort_t* __restrict__ xb,
    float* __restrict__ accg) {
  __shared__ float fstage[64 * 260];      // 66560 B, col stride 1040 B (16B pad)
  __shared__ ushort_t B16[2 * 64 * 256];  // 2 x 32 KB, swizzled bf16

  const int ntile = blockIdx.x;           // 0..15 -> n cols ntile*64..+63
  const int chunk = blockIdx.y;           // 0..15
  const int kxwin = (chunk & 7) * 32;
  const int jbase0 = (chunk >> 3) * 512;
  const int tid = threadIdx.x;
  const int wave = tid >> 6;
  const int lane = tid & 63;
  const int l15 = lane & 15;
  const int lg = lane >> 4;
  const int wrow = wave * 64;             // wave's 64 batch rows
  const int jq = lane >> 3;               // gll: j-sub
  const int slot = lane & 7;              // gll: 4-float slot
  const int ccol = tid >> 4;              // convert: column 0..63
  const int c16 = tid & 15;               // convert: chunk id

  const float* Wsel = (ntile < 8) ? W1 : W2;
  const float* Wbase = Wsel + (size_t)(ntile & 7) * 64 * 262144;

  // per-lane x cache, PACKED bf16 (t-invariant): 16 regs
  uint4 xc[4];
#pragma unroll
  for (int g = 0; g < 4; ++g)
    xc[g] = *(const uint4*)(xb + (size_t)(wrow + g * 16 + l15) * 256 + kxwin + lg * 8);

  f32x4 acc[4][4];
  const f32x4 z4 = {0.f, 0.f, 0.f, 0.f};
#pragma unroll
  for (int g = 0; g < 4; ++g)
#pragma unroll
    for (int nc = 0; nc < 4; ++nc) acc[g][nc] = z4;

  // prologue: gll(0) -> convert -> gll(1)
#pragma unroll
  for (int i = 0; i < 4; ++i) {
    int col = wave * 4 + i;
    const float* gp = Wbase + (size_t)col * 262144 +
                      (size_t)(jbase0 + jq) * 256 + kxwin + slot * 4;
    GLL16(gp, &fstage[col * 260]);
  }
  __syncthreads();
  {
    const float* sp = &fstage[ccol * 260];
    char* bb = (char*)B16 + ccol * 512;
    const int swz = (ccol & 7) << 4;
#pragma unroll
    for (int r = 0; r < 2; ++r) {
      int ch = c16 + 16 * r;
      float4 va = *(const float4*)(sp + ch * 8);
      float4 vb = *(const float4*)(sp + ch * 8 + 4);
      int jj = ch >> 2, s4 = ch & 3;
      uint4 pk;
      pk.x = cvtpk(va.x, va.y); pk.y = cvtpk(va.z, va.w);
      pk.z = cvtpk(vb.x, vb.y); pk.w = cvtpk(vb.z, vb.w);
      *(uint4*)(bb + ((jj * 64 + s4 * 16) ^ swz)) = pk;
    }
  }
  __syncthreads();
#pragma unroll
  for (int i = 0; i < 4; ++i) {
    int col = wave * 4 + i;
    const float* gp = Wbase + (size_t)col * 262144 +
                      (size_t)(jbase0 + 8 + jq) * 256 + kxwin + slot * 4;
    GLL16(gp, &fstage[col * 260]);
  }

  for (int t = 0; t < 64; ++t) {
    const char* rb = (const char*)B16 + (t & 1) * 32768;
    const int jw = jbase0 + t * 8;

#pragma unroll
    for (int hh = 0; hh < 2; ++hh) {
      // h for this half-stage: 4 j's per row (8 B), 4 row-groups = 8 regs
      uint2 hc2[4];
#pragma unroll
      for (int g = 0; g < 4; ++g)
        hc2[g] = *(const uint2*)(hb + (size_t)(wrow + g * 16 + l15) * 1024 + jw + hh * 4);

#pragma unroll
      for (int js2 = 0; js2 < 4; ++js2) {
        const int js = hh * 4 + js2;
        short8 bfr[4];
#pragma unroll
        for (int nc = 0; nc < 4; ++nc) {
          int col = nc * 16 + l15;
          int byte = col * 512 + ((js * 64 + lg * 16) ^ ((col & 7) << 4));
          bfr[nc] = *(const short8*)(rb + byte);
        }
        __builtin_amdgcn_s_setprio(1);
#pragma unroll
        for (int g = 0; g < 4; ++g) {
          unsigned hwrd = (js2 < 2) ? hc2[g].x : hc2[g].y;
          float hf = __uint_as_float((js2 & 1) ? (hwrd & 0xFFFF0000u) : (hwrd << 16));
          f32x2 hf2; hf2[0] = hf; hf2[1] = hf;
          unsigned xw[4] = {xc[g].x, xc[g].y, xc[g].z, xc[g].w};
          union { unsigned u[4]; short8 s; } av;
#pragma unroll
          for (int p = 0; p < 4; ++p) {
            f32x2 xv;
            xv[0] = __uint_as_float(xw[p] << 16);
            xv[1] = __uint_as_float(xw[p] & 0xFFFF0000u);
            f32x2 m = pkmul(xv, hf2);
            av.u[p] = cvtpk(m[0], m[1]);
          }
          short8 afr = av.s;
#pragma unroll
          for (int nc = 0; nc < 4; ++nc)
            acc[g][nc] = __builtin_amdgcn_mfma_f32_16x16x32_bf16(
                afr, bfr[nc], acc[g][nc], 0, 0, 0);
        }
        __builtin_amdgcn_s_setprio(0);
      }
    }

    if (t < 63) {
      __syncthreads();  // all reads of B16[nxt] done (t-1) + gll(t+1) drained
      {
        const float* sp = &fstage[ccol * 260];
        char* bb = (char*)B16 + ((t + 1) & 1) * 32768 + ccol * 512;
        const int swz = (ccol & 7) << 4;
#pragma unroll
        for (int r = 0; r < 2; ++r) {
          int ch = c16 + 16 * r;
          float4 va = *(const float4*)(sp + ch * 8);
          float4 vb = *(const float4*)(sp + ch * 8 + 4);
          int jj = ch >> 2, s4 = ch & 3;
          uint4 pk;
          pk.x = cvtpk(va.x, va.y); pk.y = cvtpk(va.z, va.w);
          pk.z = cvtpk(vb.x, vb.y); pk.w = cvtpk(vb.z, vb.w);
          *(uint4*)(bb + ((jj * 64 + s4 * 16) ^ swz)) = pk;
        }
      }
      __syncthreads();  // convert done; fstage free
      if (t < 62) {
        const int jb2 = jbase0 + (t + 2) * 8;
#pragma unroll
        for (int i = 0; i < 4; ++i) {
          int col = wave * 4 + i;
          const float* gp = Wbase + (size_t)col * 262144 +
                            (size_t)(jb2 + jq) * 256 + kxwin + slot * 4;
          GLL16(gp, &fstage[col * 260]);
        }
      }
    }
  }

  // epilogue: split-K accumulate (16 adds per output elem over whole grid)
#pragma unroll
  for (int g = 0; g < 4; ++g)
#pragma unroll
    for (int nc = 0; nc < 4; ++nc)
#pragma unroll
      for (int r = 0; r < 4; ++r) {
        int b = wrow + g * 16 + lg * 4 + r;
        int n = ntile * 64 + nc * 16 + l15;
        unsafeAtomicAdd(&accg[(size_t)b * 1024 + n], acc[g][nc][r]);
      }
}

// ---------------- merge = h @ Wmerge (1024x512x1024 bf16 MFMA) -------------
__device__ __forceinline__ short8 ld8bf(const ushort_t* p) {
  union { uint4 v; short8 s; } cv;
  cv.v = *(const uint4*)p;
  return cv.s;
}

__global__ __launch_bounds__(256) void merge_k(const ushort_t* __restrict__ hb,
                                               const ushort_t* __restrict__ WmT,
                                               float* __restrict__ mout) {
  const int tid = threadIdx.x;
  const int wave = tid >> 6, lane = tid & 63;
  const int l15 = lane & 15, lg = lane >> 4;
  const int m0 = blockIdx.x * 64 + (wave >> 1) * 32;
  const int n0 = blockIdx.y * 64 + (wave & 1) * 32;
  const f32x4 z4 = {0.f, 0.f, 0.f, 0.f};
  f32x4 acc[2][2];
#pragma unroll
  for (int g = 0; g < 2; ++g)
#pragma unroll
    for (int nc = 0; nc < 2; ++nc) acc[g][nc] = z4;

  for (int k = 0; k < 1024; k += 32) {
    short8 af[2], bf[2];
#pragma unroll
    for (int g = 0; g < 2; ++g)
      af[g] = ld8bf(hb + (size_t)(m0 + g * 16 + l15) * 1024 + k + lg * 8);
#pragma unroll
    for (int nc = 0; nc < 2; ++nc)
      bf[nc] = ld8bf(WmT + (size_t)(n0 + nc * 16 + l15) * 1024 + k + lg * 8);
#pragma unroll
    for (int g = 0; g < 2; ++g)
#pragma unroll
      for (int nc = 0; nc < 2; ++nc)
        acc[g][nc] = __builtin_amdgcn_mfma_f32_16x16x32_bf16(
            af[g], bf[nc], acc[g][nc], 0, 0, 0);
  }
#pragma unroll
  for (int g = 0; g < 2; ++g)
#pragma unroll
    for (int nc = 0; nc < 2; ++nc)
#pragma unroll
      for (int r = 0; r < 4; ++r)
        mout[(size_t)(m0 + g * 16 + lg * 4 + r) * 512 + n0 + nc * 16 + l15] =
            acc[g][nc][r];
}

// ---------------- finalize -------------------------------------------------
__global__ void fin_k(const float* __restrict__ accg, const float* __restrict__ mout,
                      const float* __restrict__ b1, const float* __restrict__ b2,
                      float* __restrict__ out) {
  int idx = blockIdx.x * 256 + threadIdx.x;  // 524288 total
  int b = idx >> 9, l = idx & 511;
  float m1 = accg[(size_t)b * 1024 + l];
  float m2 = accg[(size_t)b * 1024 + 512 + l];
  float st = tanhf(m1 + b1[l]);
  float u = 1.f / (1.f + expf(-(m2 + b2[l])));
  out[idx] = u * st + (1.f - u) * mout[idx];
}

extern "C" void kernel_launch(void* const* d_in, const int* in_sizes, int n_in,
                              void* d_out, int out_size, void* d_ws, size_t ws_size,
                              hipStream_t stream) {
  const float* in0 = (const float*)d_in[0];
  const float* in1 = (const float*)d_in[1];
  const float* s0  = (const float*)d_in[2];
  const float* s1  = (const float*)d_in[3];
  const float* W1  = (const float*)d_in[4];
  const float* b1  = (const float*)d_in[5];
  const float* W2  = (const float*)d_in[6];
  const float* b2  = (const float*)d_in[7];
  const float* Wm  = (const float*)d_in[8];
  float* out = (float*)d_out;

  char* ws = (char*)d_ws;
  float*    accg = (float*)(ws + 0);                          // 4 MB
  float*    mout = (float*)(ws + (4u << 20));                 // 2 MB
  ushort_t* hb   = (ushort_t*)(ws + (6u << 20));              // 2 MB
  ushort_t* xb   = (ushort_t*)(ws + (8u << 20));              // 512 KB
  ushort_t* WmT  = (ushort_t*)(ws + (8u << 20) + (512u << 10)); // 1 MB

  hipMemsetAsync(accg, 0, 4u << 20, stream);
  prep_k<<<400, 256, 0, stream>>>(in0, in1, s0, s1, Wm, hb, xb, WmT);
  bilin_k<<<dim3(16, 16), 1024, 0, stream>>>(W1, W2, hb, xb, accg);
  merge_k<<<dim3(16, 8), 256, 0, stream>>>(hb, WmT, mout);
  fin_k<<<2048, 256, 0, stream>>>(accg, mout, b1, b2, out);
}

// Round 12
// 992.194 us; speedup vs baseline: 5.3968x; 5.3968x over previous
//
#include <hip/hip_runtime.h>
#include <hip/hip_bf16.h>

// TensorizedRNN: m1/m2 = einsum('bj,bk,ljk->bl', h, x, W{1,2}) as bf16-MFMA GEMM
// with virtual A = h (outer) x, K = 1024*256 = 262144.
// B=1024, I2=256, H=512, N=1024 (W1||W2), J=1024.
//
// R12 = R9 (best measured: bilin ~865 us, total 797 us) with BARRIERS HALVED.
// Empirical law (R4-R11): allocator pins arch VGPR at 64 for these kernels;
// spill-free iff arch demand <= 64 and acc <= 32 AGPR. N=64/acc[4][4]
// variants (R10/R11) spill GB-scale -> dead end. So: N=32, acc[4][2],
// and attack R9's ~7k cyc/stage barrier-convoy stall instead:
//  - stage = 16 j (two 8-j halves), ONE barrier per stage (was per 8 j).
//  - staging in two half-batches reusing the same wa,wb pair (zero reg delta).
//  - LDS: 2 x 32 KB bf16 buffers inside the same 84 KB 1-block/CU alloc.
// Spill detector: WRITE_SIZE must stay ~72 MB.

typedef __attribute__((ext_vector_type(8))) short short8;
typedef __attribute__((ext_vector_type(4))) float f32x4;
typedef __attribute__((ext_vector_type(2))) float f32x2;
typedef unsigned short ushort_t;

// f32 pair -> packed bf16 (low16 = a, high16 = b), single HW instr
__device__ __forceinline__ unsigned cvtpk(float a, float b) {
  unsigned r;
  asm("v_cvt_pk_bf16_f32 %0, %1, %2" : "=v"(r) : "v"(a), "v"(b));
  return r;
}

// packed f32 multiply, single HW instr
__device__ __forceinline__ f32x2 pkmul(f32x2 a, f32x2 b) {
  f32x2 r;
  asm("v_pk_mul_f32 %0, %1, %2" : "=v"(r) : "v"(a), "v"(b));
  return r;
}

__device__ __forceinline__ ushort_t f2bu(float f) {
  __hip_bfloat16 b = __float2bfloat16(f);
  union { __hip_bfloat16 b; ushort_t u; } cv;
  cv.b = b;
  return cv.u;
}

// ---------------- prep: hb16[b][j], xb16[b][kx], WmergeT[l][j] (all bf16) ---
__global__ void prep_k(const float* __restrict__ in0, const float* __restrict__ in1,
                       const float* __restrict__ s0, const float* __restrict__ s1,
                       const float* __restrict__ Wm,
                       ushort_t* __restrict__ hb, ushort_t* __restrict__ xb,
                       ushort_t* __restrict__ WmT) {
  __shared__ float tl[64][65];
  const int bid = blockIdx.x, t = threadIdx.x;
  if (bid < 256) {  // hb16: 1M elems, 4096/block
#pragma unroll
    for (int i = 0; i < 4; ++i) {
      int e = bid * 4096 + i * 1024 + t * 4;
      int b = e >> 10, j = e & 1023;
      const float* src = (j < 512) ? (s0 + (size_t)b * 512 + j)
                                   : (s1 + (size_t)b * 512 + j - 512);
      float4 v = *(const float4*)src;
      ushort4 o;
      o.x = f2bu(v.x); o.y = f2bu(v.y); o.z = f2bu(v.z); o.w = f2bu(v.w);
      *(ushort4*)(hb + e) = o;
    }
  } else if (bid < 272) {  // xb16: 256K elems, 16384/block
#pragma unroll
    for (int i = 0; i < 16; ++i) {
      int e = (bid - 256) * 16384 + i * 1024 + t * 4;
      int b = e >> 8, kx = e & 255;
      const float* src = (kx < 128) ? (in0 + (size_t)b * 128 + kx)
                                    : (in1 + (size_t)b * 128 + kx - 128);
      float4 v = *(const float4*)src;
      ushort4 o;
      o.x = f2bu(v.x); o.y = f2bu(v.y); o.z = f2bu(v.z); o.w = f2bu(v.w);
      *(ushort4*)(xb + e) = o;
    }
  } else {  // Wmerge [1024][512] -> WmT [512][1024], 64x64 tiles
    int q = bid - 272;           // 0..127
    int j0 = (q >> 3) * 64;
    int l0 = (q & 7) * 64;
#pragma unroll
    for (int i = 0; i < 16; ++i) {
      int idx = i * 256 + t; int r = idx >> 6, c = idx & 63;
      tl[r][c] = Wm[(size_t)(j0 + r) * 512 + l0 + c];
    }
    __syncthreads();
#pragma unroll
    for (int i = 0; i < 16; ++i) {
      int idx = i * 256 + t; int r = idx >> 6, c = idx & 63;
      WmT[(size_t)(l0 + r) * 1024 + j0 + c] = f2bu(tl[c][r]);
    }
  }
}

// ---------------- main bilinear GEMM --------------------------------------
// grid (32 ntiles, 16 kchunks) = 512 blocks, 1024 threads (16 waves).
// Block: all 1024 batch rows x 32 n-cols; K-chunk = 512 j's x 32 kx's,
// consumed in 32 stages of 16 j (two 8-j halves per stage).
// Stage t (buf[cur] holds t's W):
//   half0: load W(t+1, j0..7) -> compute js 0..7 -> ds_write buf[nxt]
//   half1: load W(t+1, j8..15) -> compute js 8..15 -> ds_write buf[nxt]
//   ONE barrier. cur ^= 1.
__global__ __launch_bounds__(1024)
__attribute__((amdgpu_waves_per_eu(4, 4))) void bilin_k(
    const float* __restrict__ W1, const float* __restrict__ W2,
    const ushort_t* __restrict__ hb, const ushort_t* __restrict__ xb,
    float* __restrict__ accg) {
  // 2 x 32 KB bf16 buffers + pad to 84 KB: forces ONE block/CU
  // (2 blocks/CU would halve the per-wave register budget -> spill).
  __shared__ uint4 smemv[5376];  // 86016 B; buf i at byte i*32768

  const int ntile = blockIdx.x;         // 0..31 -> n cols ntile*32..+31
  const int chunk = blockIdx.y;         // 0..15
  const int kxwin = (chunk & 7) * 32;   // kx window
  const int jbase0 = (chunk >> 3) * 512;
  const int tid = threadIdx.x;
  const int wave = tid >> 6;
  const int lane = tid & 63;
  const int l15 = lane & 15;
  const int lg = lane >> 4;
  const int wrow = wave * 64;           // wave's 64 batch rows

  // W-staging role: col 0..31, j-sub 0..7 (within half), 8-float chunk 0..3
  const int scol = tid >> 5;
  const int sj = (tid & 31) >> 2;
  const int sc4 = tid & 3;
  const int swzw = (scol & 7) << 4;

  const float* Wsel = (ntile < 16) ? W1 : W2;
  const float* gW = Wsel + (size_t)(ntile & 15) * 32 * 262144 +
                    (size_t)scol * 262144 + (size_t)(jbase0 + sj) * 256 +
                    kxwin + sc4 * 8;
  // per-stage stride = 16 j * 256 = 4096 floats; half stride = 2048.

  // per-lane x cache, unpacked to f32 pairs (t-invariant): 32 regs
  f32x2 xf[4][4];
#pragma unroll
  for (int g = 0; g < 4; ++g) {
    uint4 xw = *(const uint4*)(xb + (size_t)(wrow + g * 16 + l15) * 256 + kxwin + lg * 8);
    unsigned w[4] = {xw.x, xw.y, xw.z, xw.w};
#pragma unroll
    for (int p = 0; p < 4; ++p) {
      xf[g][p][0] = __uint_as_float(w[p] << 16);
      xf[g][p][1] = __uint_as_float(w[p] & 0xFFFF0000u);
    }
  }

  f32x4 acc[4][2];
  const f32x4 z4 = {0.f, 0.f, 0.f, 0.f};
#pragma unroll
  for (int g = 0; g < 4; ++g)
#pragma unroll
    for (int nc = 0; nc < 2; ++nc) acc[g][nc] = z4;

  // prologue: stage t=0 (both halves) into buf[0]
#pragma unroll
  for (int hh = 0; hh < 2; ++hh) {
    const float* gp = gW + hh * 2048;
    float4 wa = *(const float4*)gp;
    float4 wb = *(const float4*)(gp + 4);
    uint4 pk;
    pk.x = cvtpk(wa.x, wa.y); pk.y = cvtpk(wa.z, wa.w);
    pk.z = cvtpk(wb.x, wb.y); pk.w = cvtpk(wb.z, wb.w);
    int wbyte = scol * 1024 + ((((hh * 8 + sj) * 64) + sc4 * 16) ^ swzw);
    *(uint4*)((char*)smemv + wbyte) = pk;
  }
  __syncthreads();

  int cur = 0;
  for (int t = 0; t < 32; ++t) {
    const int nxt = cur ^ 1;
    const char* rb = (const char*)smemv + cur * 32768;
    const int jw = jbase0 + t * 16;

#pragma unroll
    for (int hh = 0; hh < 2; ++hh) {
      // issue next-stage half's W loads early (hidden under this half's MFMAs)
      float4 wa, wb;
      if (t < 31) {
        const float* gp = gW + (size_t)(t + 1) * 4096 + hh * 2048;
        wa = *(const float4*)gp;
        wb = *(const float4*)(gp + 4);
      }

      // h for this half: 8 j's per row (16 B), 4 row-groups
      uint4 hc[4];
#pragma unroll
      for (int g = 0; g < 4; ++g)
        hc[g] = *(const uint4*)(hb + (size_t)(wrow + g * 16 + l15) * 1024 + jw + hh * 8);

      // register double-buffer for B fragments: preload js_local=0
      short8 bfr[2][2];
#pragma unroll
      for (int nc = 0; nc < 2; ++nc) {
        int col = nc * 16 + l15;
        int byte = col * 1024 + (((hh * 8) * 64 + lg * 16) ^ ((col & 7) << 4));
        bfr[0][nc] = *(const short8*)(rb + byte);
      }

#pragma unroll
      for (int js = 0; js < 8; ++js) {
        const int pb = js & 1, nb = pb ^ 1;
        const int js16 = hh * 8 + js;
        if (js < 7) {
#pragma unroll
          for (int nc = 0; nc < 2; ++nc) {
            int col = nc * 16 + l15;
            int byte = col * 1024 + (((js16 + 1) * 64 + lg * 16) ^ ((col & 7) << 4));
            bfr[nb][nc] = *(const short8*)(rb + byte);
          }
        }
        __builtin_amdgcn_s_setprio(1);
#pragma unroll
        for (int g = 0; g < 4; ++g) {
          unsigned hwrd = (js < 2) ? hc[g].x : (js < 4) ? hc[g].y
                         : (js < 6) ? hc[g].z : hc[g].w;
          float hf = __uint_as_float((js & 1) ? (hwrd & 0xFFFF0000u) : (hwrd << 16));
          f32x2 hf2; hf2[0] = hf; hf2[1] = hf;
          union { unsigned u[4]; short8 s; } av;
#pragma unroll
          for (int p = 0; p < 4; ++p) {
            f32x2 m = pkmul(xf[g][p], hf2);
            av.u[p] = cvtpk(m[0], m[1]);
          }
          short8 afr = av.s;
#pragma unroll
          for (int nc = 0; nc < 2; ++nc)
            acc[g][nc] = __builtin_amdgcn_mfma_f32_16x16x32_bf16(
                afr, bfr[pb][nc], acc[g][nc], 0, 0, 0);
        }
        __builtin_amdgcn_s_setprio(0);
      }

      // write this half's staged W into buf[nxt] (vmcnt wait lands here)
      if (t < 31) {
        uint4 pk;
        pk.x = cvtpk(wa.x, wa.y); pk.y = cvtpk(wa.z, wa.w);
        pk.z = cvtpk(wb.x, wb.y); pk.w = cvtpk(wb.z, wb.w);
        int wbyte = scol * 1024 + ((((hh * 8 + sj) * 64) + sc4 * 16) ^ swzw);
        *(uint4*)((char*)smemv + nxt * 32768 + wbyte) = pk;
      }
    }

    __syncthreads();  // buf[nxt] complete; buf[cur] reads done
    cur = nxt;
  }

  // epilogue: split-K accumulate (16 adds per output elem over whole grid)
#pragma unroll
  for (int g = 0; g < 4; ++g)
#pragma unroll
    for (int nc = 0; nc < 2; ++nc)
#pragma unroll
      for (int r = 0; r < 4; ++r) {
        int b = wrow + g * 16 + lg * 4 + r;
        int n = ntile * 32 + nc * 16 + l15;
        unsafeAtomicAdd(&accg[(size_t)b * 1024 + n], acc[g][nc][r]);
      }
}

// ---------------- merge = h @ Wmerge (1024x512x1024 bf16 MFMA) -------------
__device__ __forceinline__ short8 ld8bf(const ushort_t* p) {
  union { uint4 v; short8 s; } cv;
  cv.v = *(const uint4*)p;
  return cv.s;
}

__global__ __launch_bounds__(256) void merge_k(const ushort_t* __restrict__ hb,
                                               const ushort_t* __restrict__ WmT,
                                               float* __restrict__ mout) {
  const int tid = threadIdx.x;
  const int wave = tid >> 6, lane = tid & 63;
  const int l15 = lane & 15, lg = lane >> 4;
  const int m0 = blockIdx.x * 64 + (wave >> 1) * 32;
  const int n0 = blockIdx.y * 64 + (wave & 1) * 32;
  const f32x4 z4 = {0.f, 0.f, 0.f, 0.f};
  f32x4 acc[2][2];
#pragma unroll
  for (int g = 0; g < 2; ++g)
#pragma unroll
    for (int nc = 0; nc < 2; ++nc) acc[g][nc] = z4;

  for (int k = 0; k < 1024; k += 32) {
    short8 af[2], bf[2];
#pragma unroll
    for (int g = 0; g < 2; ++g)
      af[g] = ld8bf(hb + (size_t)(m0 + g * 16 + l15) * 1024 + k + lg * 8);
#pragma unroll
    for (int nc = 0; nc < 2; ++nc)
      bf[nc] = ld8bf(WmT + (size_t)(n0 + nc * 16 + l15) * 1024 + k + lg * 8);
#pragma unroll
    for (int g = 0; g < 2; ++g)
#pragma unroll
      for (int nc = 0; nc < 2; ++nc)
        acc[g][nc] = __builtin_amdgcn_mfma_f32_16x16x32_bf16(
            af[g], bf[nc], acc[g][nc], 0, 0, 0);
  }
#pragma unroll
  for (int g = 0; g < 2; ++g)
#pragma unroll
    for (int nc = 0; nc < 2; ++nc)
#pragma unroll
      for (int r = 0; r < 4; ++r)
        mout[(size_t)(m0 + g * 16 + lg * 4 + r) * 512 + n0 + nc * 16 + l15] =
            acc[g][nc][r];
}

// ---------------- finalize -------------------------------------------------
__global__ void fin_k(const float* __restrict__ accg, const float* __restrict__ mout,
                      const float* __restrict__ b1, const float* __restrict__ b2,
                      float* __restrict__ out) {
  int idx = blockIdx.x * 256 + threadIdx.x;  // 524288 total
  int b = idx >> 9, l = idx & 511;
  float m1 = accg[(size_t)b * 1024 + l];
  float m2 = accg[(size_t)b * 1024 + 512 + l];
  float st = tanhf(m1 + b1[l]);
  float u = 1.f / (1.f + expf(-(m2 + b2[l])));
  out[idx] = u * st + (1.f - u) * mout[idx];
}

extern "C" void kernel_launch(void* const* d_in, const int* in_sizes, int n_in,
                              void* d_out, int out_size, void* d_ws, size_t ws_size,
                              hipStream_t stream) {
  const float* in0 = (const float*)d_in[0];
  const float* in1 = (const float*)d_in[1];
  const float* s0  = (const float*)d_in[2];
  const float* s1  = (const float*)d_in[3];
  const float* W1  = (const float*)d_in[4];
  const float* b1  = (const float*)d_in[5];
  const float* W2  = (const float*)d_in[6];
  const float* b2  = (const float*)d_in[7];
  const float* Wm  = (const float*)d_in[8];
  float* out = (float*)d_out;

  char* ws = (char*)d_ws;
  float*    accg = (float*)(ws + 0);                          // 4 MB
  float*    mout = (float*)(ws + (4u << 20));                 // 2 MB
  ushort_t* hb   = (ushort_t*)(ws + (6u << 20));              // 2 MB
  ushort_t* xb   = (ushort_t*)(ws + (8u << 20));              // 512 KB
  ushort_t* WmT  = (ushort_t*)(ws + (8u << 20) + (512u << 10)); // 1 MB

  hipMemsetAsync(accg, 0, 4u << 20, stream);
  prep_k<<<400, 256, 0, stream>>>(in0, in1, s0, s1, Wm, hb, xb, WmT);
  bilin_k<<<dim3(32, 16), 1024, 0, stream>>>(W1, W2, hb, xb, accg);
  merge_k<<<dim3(16, 8), 256, 0, stream>>>(hb, WmT, mout);
  fin_k<<<2048, 256, 0, stream>>>(accg, mout, b1, b2, out);
}